// Round 11
// baseline (20102.342 us; speedup 1.0000x reference)
//
#include <hip/hip_runtime.h>
#include <hip/hip_cooperative_groups.h>
#include <math.h>

namespace cg = cooperative_groups;

#define SS 512
#define BB 64
#define II 512
#define HH 1024

typedef __attribute__((ext_vector_type(8))) __bf16 bf16x8;
typedef __attribute__((ext_vector_type(4))) float f32x4;

// ---------------- ws layout ----------------
// wpack : 256 wg * 48 iters * 64 lanes * 8 bf16 = 6,291,456 elems (12.58 MB)
// hbf0/1: 2 * 65536 bf16
#define WPACK_ELEMS (256u * 48u * 64u * 8u)
#define HBF_ELEMS   (BB * HH)

struct PersistParams {
  const float* x;        // [S,B,I] fp32
  const __bf16* wpack;   // packed weights (per-lane fragments)
  __bf16* hbf0;          // [B,H] bf16 double buffer (even steps read this)
  __bf16* hbf1;
  const float* c0;       // [B,H] fp32 initial cell
  const float* bx[4];    // biases (f,i,o,c)
  const float* bh[4];
  float* out;            // [S*B*H + 2*B*H] fp32
};

// Persistent LSTM: one cooperative kernel, 256 wgs x 1024 thr (16 waves, 1 wg/CU).
// wg wb owns h-rows [4wb,4wb+4) x 4 gates x 64 batches. Wave (ks=w>>2, bg=w&3):
// batches [16bg,16bg+16), K-slice ks. Weights: 12 bf16x8 fragments per lane,
// held in VGPRs for all 512 steps. c-state + biases in epilogue-thread registers.
__global__ __launch_bounds__(1024, 4) void lstm_persist(PersistParams p) {
  cg::grid_group grid = cg::this_grid();

  __shared__ float part[4][4][16][17];  // [ks][bg][row][col]
  __shared__ float pre[4][16][17];      // [bg][row][col]

  const int wb = blockIdx.x;
  const int t = threadIdx.x;
  const int w = t >> 6;
  const int lane = t & 63;
  const int bg = w & 3;
  const int ks = w >> 2;

  const int kof  = (lane >> 4) * 8;
  const int bcol = bg * 16 + (lane & 15);

  // ---- one-time: weights into VGPRs (12 fragments = 48 VGPRs) ----
  const __bf16* ap = p.wpack + (((size_t)wb * 48) * 64 + lane) * 8;
  bf16x8 afr[12];
#pragma unroll
  for (int j = 0; j < 8; ++j)
    afr[j] = *(const bf16x8*)(ap + (size_t)(ks + 4 * j) * 512);
#pragma unroll
  for (int j = 0; j < 4; ++j)
    afr[8 + j] = *(const bf16x8*)(ap + (size_t)(32 + ks + 4 * j) * 512);

  // ---- one-time: epilogue-thread persistent state ----
  const int eb    = t >> 2;      // batch 0..63 (valid when t<256)
  const int hsub  = t & 3;
  const int hg    = wb * 4 + hsub;
  const int ebg   = eb >> 4;
  const int ebc   = eb & 15;
  float creg = 0.f, bsum0 = 0.f, bsum1 = 0.f, bsum2 = 0.f, bsum3 = 0.f;
  if (t < 256) {
    const size_t ci = (size_t)eb * HH + hg;
    creg  = p.c0[ci];
    bsum0 = p.bx[0][hg] + p.bh[0][hg];
    bsum1 = p.bx[1][hg] + p.bh[1][hg];
    bsum2 = p.bx[2][hg] + p.bh[2][hg];
    bsum3 = p.bx[3][hg] + p.bh[3][hg];
  }

  const int drow = (lane >> 4) * 4;

#pragma unroll 1
  for (int s = 0; s < SS; ++s) {
    const __bf16* hbin = ((s & 1) ? p.hbf1 : p.hbf0) + (size_t)bcol * HH + kof;
    const float*  bxp  = p.x + ((size_t)s * BB + bcol) * II + kof;

    f32x4 acc = {0.f, 0.f, 0.f, 0.f};
#pragma unroll
    for (int j = 0; j < 8; ++j) {
      bf16x8 b = *(const bf16x8*)(hbin + (ks + 4 * j) * 32);
      acc = __builtin_amdgcn_mfma_f32_16x16x32_bf16(afr[j], b, acc, 0, 0, 0);
    }
#pragma unroll
    for (int j = 0; j < 4; ++j) {
      const float* xp = bxp + (ks + 4 * j) * 32;
      float4 x0 = *(const float4*)(xp);
      float4 x1 = *(const float4*)(xp + 4);
      bf16x8 b;
      b[0] = (__bf16)x0.x; b[1] = (__bf16)x0.y; b[2] = (__bf16)x0.z; b[3] = (__bf16)x0.w;
      b[4] = (__bf16)x1.x; b[5] = (__bf16)x1.y; b[6] = (__bf16)x1.z; b[7] = (__bf16)x1.w;
      acc = __builtin_amdgcn_mfma_f32_16x16x32_bf16(afr[8 + j], b, acc, 0, 0, 0);
    }

    part[ks][bg][drow + 0][lane & 15] = acc[0];
    part[ks][bg][drow + 1][lane & 15] = acc[1];
    part[ks][bg][drow + 2][lane & 15] = acc[2];
    part[ks][bg][drow + 3][lane & 15] = acc[3];
    __syncthreads();

    {
      const int rbg = t >> 8;
      const int row = (t >> 4) & 15;
      const int bc  = t & 15;
      pre[rbg][row][bc] = part[0][rbg][row][bc] + part[1][rbg][row][bc]
                        + part[2][rbg][row][bc] + part[3][rbg][row][bc];
    }
    __syncthreads();

    if (t < 256) {
      float pf = pre[ebg][ 0 + hsub][ebc] + bsum0;
      float pi = pre[ebg][ 4 + hsub][ebc] + bsum1;
      float po = pre[ebg][ 8 + hsub][ebc] + bsum2;
      float pc = pre[ebg][12 + hsub][ebc] + bsum3;

      float fg = 1.f / (1.f + __expf(-pf));
      float ig = 1.f / (1.f + __expf(-pi));
      float og = 1.f / (1.f + __expf(-po));
      float cg_ = tanhf(pc);

      float cn = fg * creg + ig * cg_;
      float hn = og * tanhf(cn);
      creg = cn;

      const size_t ci = (size_t)eb * HH + hg;
      p.out[(size_t)s * BB * HH + ci] = hn;
      ((s & 1) ? p.hbf0 : p.hbf1)[ci] = (__bf16)hn;   // next step's input
      if (s == SS - 1) {
        p.out[(size_t)SS * BB * HH + ci] = hn;             // h_last
        p.out[(size_t)SS * BB * HH + BB * HH + ci] = cn;   // c_last
      }
    }

    grid.sync();   // device-scope release/acquire included (ockl grid_sync)
  }
}

struct PackParams {
  const float* Wh[4];
  const float* Wx[4];
  __bf16* wpack;
};

// Pack fp32 weights into per-(wg,iter,lane) bf16x8 fragments.
__global__ __launch_bounds__(256) void pack_weights(PackParams p) {
  const int wb = blockIdx.x;
  const int t = threadIdx.x;
  const int it2 = t >> 6;
  const int lane = t & 63;
  const int r16 = lane & 15;
  const int g = r16 >> 2;
  const int hrow = wb * 4 + (r16 & 3);
  const int kof = (lane >> 4) * 8;
  for (int itb = 0; itb < 12; ++itb) {
    const int it = itb * 4 + it2;
    const float* src;
    if (it < 32) src = p.Wh[g] + (size_t)hrow * HH + it * 32 + kof;
    else         src = p.Wx[g] + (size_t)hrow * II + (it - 32) * 32 + kof;
    float4 s0 = *(const float4*)(src);
    float4 s1 = *(const float4*)(src + 4);
    bf16x8 v;
    v[0] = (__bf16)s0.x; v[1] = (__bf16)s0.y; v[2] = (__bf16)s0.z; v[3] = (__bf16)s0.w;
    v[4] = (__bf16)s1.x; v[5] = (__bf16)s1.y; v[6] = (__bf16)s1.z; v[7] = (__bf16)s1.w;
    *(bf16x8*)(p.wpack + (((size_t)wb * 48 + it) * 64 + lane) * 8) = v;
  }
}

__global__ __launch_bounds__(256) void prep_state(const float* h0, __bf16* hbf0) {
  const int i = blockIdx.x * 256 + threadIdx.x;  // grid 256 -> 65536
  hbf0[i] = (__bf16)h0[i];
}

extern "C" void kernel_launch(void* const* d_in, const int* in_sizes, int n_in,
                              void* d_out, int out_size, void* d_ws, size_t ws_size,
                              hipStream_t stream) {
  (void)in_sizes; (void)n_in; (void)out_size; (void)ws_size;

  __bf16* wsb = (__bf16*)d_ws;
  __bf16* wpack = wsb;
  __bf16* hbf0 = wsb + WPACK_ELEMS;
  __bf16* hbf1 = hbf0 + HBF_ELEMS;

  // dict order: x,h,c, Wfx,bfx,Wfh,bfh, Wix,bix,Wih,bih, Wox,b_ox,Woh,boh, Wcx,bcx,Wch,bch
  PackParams pk;
  pk.Wx[0] = (const float*)d_in[3];  pk.Wh[0] = (const float*)d_in[5];
  pk.Wx[1] = (const float*)d_in[7];  pk.Wh[1] = (const float*)d_in[9];
  pk.Wx[2] = (const float*)d_in[11]; pk.Wh[2] = (const float*)d_in[13];
  pk.Wx[3] = (const float*)d_in[15]; pk.Wh[3] = (const float*)d_in[17];
  pk.wpack = wpack;

  PersistParams p;
  p.x = (const float*)d_in[0];
  p.wpack = wpack;
  p.hbf0 = hbf0;
  p.hbf1 = hbf1;
  p.c0 = (const float*)d_in[2];
  p.bx[0] = (const float*)d_in[4];  p.bh[0] = (const float*)d_in[6];
  p.bx[1] = (const float*)d_in[8];  p.bh[1] = (const float*)d_in[10];
  p.bx[2] = (const float*)d_in[12]; p.bh[2] = (const float*)d_in[14];
  p.bx[3] = (const float*)d_in[16]; p.bh[3] = (const float*)d_in[18];
  p.out = (float*)d_out;

  pack_weights<<<dim3(256), dim3(256), 0, stream>>>(pk);
  prep_state<<<dim3(256), dim3(256), 0, stream>>>((const float*)d_in[1], hbf0);

  void* kargs[] = {&p};
  hipLaunchCooperativeKernel((const void*)lstm_persist, dim3(256), dim3(1024),
                             kargs, 0, stream);
}